// Round 11
// baseline (37.557 us; speedup 1.0000x reference)
//
#include <hip/hip_runtime.h>

// Memristor dense fwd. q = max_w/9 enters linearly:
//   y[b,j] = 0.5*[ A + biasA + q*(B + biasB) ]
//   A = sum_r s*(wp*t^gp - wn*t^gn),  B = sum_r s*(t^gp - t^gn)
//   biasA = bp*n_pos - bn*n_neg, biasB = n_pos - n_neg  (bias row t=2 -> t^g = n)
// t = max(2|x|,1e-12), s = sign(x), L = log2(t), g = log2(n_param).
// Inner loop (wd = wp-wn staged): u = ep-en; B += s*u; A += s*(wp*u + wd*en).
// High-occupancy variant: 18 KiB LDS, 8 blocks/CU (32 waves/CU), 2048 blocks.
// Main: A,B partials + per-tile weight max. Reduce: q + z-reduce + combine.

#define N_IN 1024
#define N_OUT 512
#define NB 128
#define Z 16            // r-split across grid.z (64 rows per block)
#define RPC 16          // rows per staged chunk (4 chunks per block)
#define JT 64
#define BT 8

typedef float v2f __attribute__((ext_vector_type(2)));

// ws float layout: [0..127] tile-max slots (slot = jx*16+bz);
//   A partials at AOFF: [Z][NB][N_OUT] = 4 MiB; B partials at BOFF: 4 MiB.
#define AOFF 1024
#define BOFF (1024 + Z * NB * N_OUT)

__launch_bounds__(256, 8)
__global__ void memristor_mainAB(const float* __restrict__ x,
                                 const float* __restrict__ wp,
                                 const float* __restrict__ wn,
                                 const float* __restrict__ npar,
                                 float* __restrict__ ws) {
    // Wg[r][arr][grp][4]: arr 0=wp, 1=wd=wp-wn, 2=gp, 3=gn; grp XOR-swizzled by r
    __shared__ float Wg[RPC][4][16][4];   // 16 KiB
    __shared__ float Lx[RPC][BT][2];      // 1 KiB: (L, s), r-major (broadcast reads)

    const int tid = threadIdx.x;
    const int jx = blockIdx.x, by = blockIdx.y, bz = blockIdx.z;
    const int j0 = jx * JT;
    const int b0 = by * BT;

    const int tj2 = tid & 31;       // 2-j group (j pair tj2*2, tj2*2+1)
    const int bl  = tid >> 5;       // 0..7: b row
    const int g4  = tj2 >> 1;       // float4 group in Wg
    const int sub = (tj2 & 1) * 2;  // float2 within group

    v2f accA = {0.f, 0.f};
    v2f accB = {0.f, 0.f};
    float m_w = 0.0f;               // tile weight max (free: data already in regs)

    for (int c = 0; c < 4; ++c) {
        const int rbase = bz * 64 + c * RPC;
        __syncthreads();   // protect LDS reuse across chunks
        if (tid < 128) {   // stage x: 8 b x 16 r, one float per thread
            int bl8 = tid >> 4;
            int rq = tid & 15;
            float val = x[(b0 + bl8) * N_IN + rbase + rq];
            float s = (val > 0.f) ? 1.f : ((val < 0.f) ? -1.f : 0.f);
            float t = fmaxf(2.f * fabsf(val), 1e-12f);
            Lx[rq][bl8][0] = __builtin_amdgcn_logf(t);   // log2
            Lx[rq][bl8][1] = s;
        }
        {   // stage weights (wp, wd) + gammas: 16 r-rows x 64 j-cols; 4 j per thread
            int rr = tid >> 4;          // 0..15
            int cgp = tid & 15;         // 0..15 (4-col group)
            int pg = cgp ^ rr;          // XOR swizzle
            {
                const float* prow = &wp[(rbase + rr) * N_OUT + j0 + cgp * 4];
                const float* nrow = &wn[(rbase + rr) * N_OUT + j0 + cgp * 4];
                float4 pa = *(const float4*)&prow[0];
                float4 na = *(const float4*)&nrow[0];
                *(float4*)&Wg[rr][0][pg][0] = pa;
                *(float4*)&Wg[rr][1][pg][0] = make_float4(pa.x - na.x, pa.y - na.y,
                                                          pa.z - na.z, pa.w - na.w);
                m_w = fmaxf(m_w, fmaxf(fmaxf(pa.x, pa.y), fmaxf(pa.z, pa.w)));
                m_w = fmaxf(m_w, fmaxf(fmaxf(na.x, na.y), fmaxf(na.z, na.w)));
            }
            {
                const float* nrow = &npar[(rbase + rr) * (2 * N_OUT) + 2 * j0 + cgp * 8];
                float4 f0 = *(const float4*)&nrow[0];    // p0 n0 p1 n1
                float4 f1 = *(const float4*)&nrow[4];    // p2 n2 p3 n3
                *(float4*)&Wg[rr][2][pg][0] = make_float4(
                    __builtin_amdgcn_logf(f0.x), __builtin_amdgcn_logf(f0.z),
                    __builtin_amdgcn_logf(f1.x), __builtin_amdgcn_logf(f1.z));
                *(float4*)&Wg[rr][3][pg][0] = make_float4(
                    __builtin_amdgcn_logf(f0.y), __builtin_amdgcn_logf(f0.w),
                    __builtin_amdgcn_logf(f1.y), __builtin_amdgcn_logf(f1.w));
            }
        }
        __syncthreads();

        #pragma unroll 8
        for (int r = 0; r < RPC; ++r) {
            const float* wbase = &Wg[r][0][g4 ^ r][sub];
            v2f w_p = *(const v2f*)&wbase[0];
            v2f w_d = *(const v2f*)&wbase[64];    // arr stride = 16 grp * 4 = 64 floats
            v2f g_p = *(const v2f*)&wbase[128];
            v2f g_n = *(const v2f*)&wbase[192];
            float2 Ls = *(const float2*)&Lx[r][bl][0];
            const float L = Ls.x, s = Ls.y;

            v2f ap = L * g_p;                     // v_pk_mul
            v2f an = L * g_n;
            v2f ep, en;
            ep.x = __builtin_amdgcn_exp2f(ap.x); ep.y = __builtin_amdgcn_exp2f(ap.y);
            en.x = __builtin_amdgcn_exp2f(an.x); en.y = __builtin_amdgcn_exp2f(an.y);

            v2f u = ep - en;                      // v_pk_add
            accB += s * u;                        // v_pk_fma (s broadcast)
            v2f v = w_p * u + w_d * en;           // pk_mul + pk_fma
            accA += s * v;
        }
    }

    // ---- write A/B partials (coalesced float2) ----
    {
        size_t base = (size_t)bz * (NB * N_OUT) + (b0 + bl) * N_OUT + j0 + tj2 * 2;
        *(float2*)&ws[AOFF + base] = make_float2(accA.x, accA.y);
        *(float2*)&ws[BOFF + base] = make_float2(accB.x, accB.y);
    }

    // ---- tile weight-max slot (one writer set: by==0) ----
    if (by == 0) {
        __syncthreads();                 // all Lx reads done; safe to alias
        float* qred = &Lx[0][0][0];
        #pragma unroll
        for (int off = 32; off; off >>= 1) m_w = fmaxf(m_w, __shfl_xor(m_w, off));
        if ((tid & 63) == 0) qred[tid >> 6] = m_w;
        __syncthreads();
        if (tid == 0)
            ws[jx * Z + bz] = fmaxf(fmaxf(qred[0], qred[1]), fmaxf(qred[2], qred[3]));
    }
}

__global__ void reduce_combine(const float* __restrict__ ws,
                               const float* __restrict__ bp,
                               const float* __restrict__ bn,
                               const float* __restrict__ npar,
                               float* __restrict__ out) {
    __shared__ float qs[4];
    const int tid = threadIdx.x;

    // q = max(128 tile slots, bias weights) / 9
    float mm = (tid < 128) ? ws[tid] : 0.0f;
    float2 a2 = ((const float2*)bp)[tid];     // 512 floats over 256 threads
    float2 b2 = ((const float2*)bn)[tid];
    mm = fmaxf(mm, fmaxf(fmaxf(a2.x, a2.y), fmaxf(b2.x, b2.y)));
    #pragma unroll
    for (int off = 32; off; off >>= 1) mm = fmaxf(mm, __shfl_xor(mm, off));
    if ((tid & 63) == 0) qs[tid >> 6] = mm;
    __syncthreads();
    const float q = fmaxf(fmaxf(qs[0], qs[1]), fmaxf(qs[2], qs[3])) * (1.0f / 9.0f);

    const int g = blockIdx.x * 256 + tid;     // float4 index, 0..16383
    const float4* A4 = (const float4*)(ws + AOFF);
    const float4* B4 = (const float4*)(ws + BOFF);
    float ax = 0.f, ay = 0.f, az = 0.f, aw = 0.f;
    float bx = 0.f, byy = 0.f, bz2 = 0.f, bw = 0.f;
    #pragma unroll
    for (int z = 0; z < Z; ++z) {
        float4 va = A4[(size_t)z * (NB * N_OUT / 4) + g];
        float4 vb = B4[(size_t)z * (NB * N_OUT / 4) + g];
        ax += va.x; ay += va.y; az += va.z; aw += va.w;
        bx += vb.x; byy += vb.y; bz2 += vb.z; bw += vb.w;
    }
    const int j = (g * 4) & (N_OUT - 1);
    float4 bpv = *(const float4*)&bp[j];
    float4 bnv = *(const float4*)&bn[j];
    const float* nrow = &npar[N_IN * (2 * N_OUT) + 2 * j];
    float4 n0 = *(const float4*)&nrow[0];     // (np0,nn0,np1,nn1)
    float4 n1 = *(const float4*)&nrow[4];     // (np2,nn2,np3,nn3)
    float y0 = 0.5f * (ax + bpv.x * n0.x - bnv.x * n0.y + q * (bx  + n0.x - n0.y));
    float y1 = 0.5f * (ay + bpv.y * n0.z - bnv.y * n0.w + q * (byy + n0.z - n0.w));
    float y2 = 0.5f * (az + bpv.z * n1.x - bnv.z * n1.y + q * (bz2 + n1.x - n1.y));
    float y3 = 0.5f * (aw + bpv.w * n1.z - bnv.w * n1.w + q * (bw  + n1.z - n1.w));
    ((float4*)out)[g] = make_float4(y0, y1, y2, y3);
}

extern "C" void kernel_launch(void* const* d_in, const int* in_sizes, int n_in,
                              void* d_out, int out_size, void* d_ws, size_t ws_size,
                              hipStream_t stream) {
    const float* x    = (const float*)d_in[0];
    const float* wp   = (const float*)d_in[1];
    const float* wn   = (const float*)d_in[2];
    const float* bp   = (const float*)d_in[3];
    const float* bn   = (const float*)d_in[4];
    const float* npar = (const float*)d_in[5];
    float* out = (float*)d_out;
    float* ws  = (float*)d_ws;   // 128 slots + 8 MiB A/B partials

    dim3 grid(N_OUT / JT, NB / BT, Z);   // (8,16,16) = 2048 blocks, 8/CU
    memristor_mainAB<<<grid, 256, 0, stream>>>(x, wp, wn, npar, ws);

    reduce_combine<<<(NB * N_OUT / 4) / 256, 256, 0, stream>>>(ws, bp, bn, npar, out);
}

// Round 12
// 35.189 us; speedup vs baseline: 1.0673x; 1.0673x over previous
//
#include <hip/hip_runtime.h>

// Memristor dense fwd. q = max_w/9 enters linearly:
//   y[b,j] = 0.5*[ A + biasA + q*(B + biasB) ]
//   A = sum_r s*(wp*t^gp - wn*t^gn),  B = sum_r s*(t^gp - t^gn)
//   biasA = bp*n_pos - bn*n_neg, biasB = n_pos - n_neg  (bias row t=2 -> t^g = n)
// t = max(2|x|,1e-12), s = sign(x), L = log2(t), g = log2(n_param).
// Inner loop (wd = wp-wn staged): u = ep-en; B += s*u; A += s*(wp*u + wd*en).
// R12: occupancy experiment at constant staging redundancy (NB/BT=8):
//   Z=32 -> 2048 blocks, 18 KiB LDS, launch_bounds(256,8) -> 32 waves/CU.

#define N_IN 1024
#define N_OUT 512
#define NB 128
#define Z 32            // r-split across grid.z (32 rows per block)
#define RPC 16          // rows per staged chunk (2 chunks per block)
#define JT 64
#define BT 16

typedef float v2f __attribute__((ext_vector_type(2)));

// ws float layout: [0..255] tile-max slots (slot = jx*32+bz);
//   A partials at AOFF: [Z][NB][N_OUT] = 8 MiB; B partials at BOFF: 8 MiB.
#define AOFF 1024
#define BOFF (1024 + Z * NB * N_OUT)

__launch_bounds__(256, 8)
__global__ void memristor_mainAB(const float* __restrict__ x,
                                 const float* __restrict__ wp,
                                 const float* __restrict__ wn,
                                 const float* __restrict__ npar,
                                 float* __restrict__ ws) {
    // Wg[r][arr][grp][4]: arr 0=wp, 1=wd=wp-wn, 2=gp, 3=gn; grp XOR-swizzled by r
    __shared__ float Wg[RPC][4][16][4];   // 16 KiB
    __shared__ float Lx[RPC][BT][2];      // 2 KiB: (L, s), r-major (broadcast reads)

    const int tid = threadIdx.x;
    const int jx = blockIdx.x, by = blockIdx.y, bz = blockIdx.z;
    const int j0 = jx * JT;
    const int b0 = by * BT;

    const int tj4 = tid & 15;       // j group (4 cols)
    const int bl  = tid >> 4;       // 0..15: b row

    v2f accA01 = {0.f, 0.f}, accA23 = {0.f, 0.f};
    v2f accB01 = {0.f, 0.f}, accB23 = {0.f, 0.f};
    float m_w = 0.0f;               // tile weight max (free: data already in regs)

    for (int c = 0; c < 2; ++c) {
        const int rbase = bz * 32 + c * RPC;
        __syncthreads();   // protect LDS reuse across chunks
        {   // stage x: 16 b x 16 r, one float per thread
            int bl16 = tid >> 4;
            int rq = tid & 15;
            float val = x[(b0 + bl16) * N_IN + rbase + rq];
            float s = (val > 0.f) ? 1.f : ((val < 0.f) ? -1.f : 0.f);
            float t = fmaxf(2.f * fabsf(val), 1e-12f);
            Lx[rq][bl16][0] = __builtin_amdgcn_logf(t);   // log2
            Lx[rq][bl16][1] = s;
        }
        {   // stage weights (wp, wd) + gammas: 16 r-rows x 64 j-cols; 4 j per thread
            int rr = tid >> 4;          // 0..15
            int cgp = tid & 15;         // 0..15 (4-col group)
            int pg = cgp ^ rr;          // XOR swizzle
            {
                const float* prow = &wp[(rbase + rr) * N_OUT + j0 + cgp * 4];
                const float* nrow = &wn[(rbase + rr) * N_OUT + j0 + cgp * 4];
                float4 pa = *(const float4*)&prow[0];
                float4 na = *(const float4*)&nrow[0];
                *(float4*)&Wg[rr][0][pg][0] = pa;
                *(float4*)&Wg[rr][1][pg][0] = make_float4(pa.x - na.x, pa.y - na.y,
                                                          pa.z - na.z, pa.w - na.w);
                m_w = fmaxf(m_w, fmaxf(fmaxf(pa.x, pa.y), fmaxf(pa.z, pa.w)));
                m_w = fmaxf(m_w, fmaxf(fmaxf(na.x, na.y), fmaxf(na.z, na.w)));
            }
            {
                const float* nrow = &npar[(rbase + rr) * (2 * N_OUT) + 2 * j0 + cgp * 8];
                float4 f0 = *(const float4*)&nrow[0];    // p0 n0 p1 n1
                float4 f1 = *(const float4*)&nrow[4];    // p2 n2 p3 n3
                *(float4*)&Wg[rr][2][pg][0] = make_float4(
                    __builtin_amdgcn_logf(f0.x), __builtin_amdgcn_logf(f0.z),
                    __builtin_amdgcn_logf(f1.x), __builtin_amdgcn_logf(f1.z));
                *(float4*)&Wg[rr][3][pg][0] = make_float4(
                    __builtin_amdgcn_logf(f0.y), __builtin_amdgcn_logf(f0.w),
                    __builtin_amdgcn_logf(f1.y), __builtin_amdgcn_logf(f1.w));
            }
        }
        __syncthreads();

        #pragma unroll 8
        for (int r = 0; r < RPC; ++r) {
            const float4* wrow = (const float4*)&Wg[r][0][tj4 ^ r][0];
            float4 w_p = wrow[0];
            float4 w_d = wrow[16];
            float4 g_p = wrow[32];
            float4 g_n = wrow[48];
            float2 Ls = *(const float2*)&Lx[r][bl][0];
            const float L = Ls.x, s = Ls.y;

            v2f wp01 = {w_p.x, w_p.y}, wp23 = {w_p.z, w_p.w};
            v2f wd01 = {w_d.x, w_d.y}, wd23 = {w_d.z, w_d.w};
            v2f gp01 = {g_p.x, g_p.y}, gp23 = {g_p.z, g_p.w};
            v2f gn01 = {g_n.x, g_n.y}, gn23 = {g_n.z, g_n.w};

            v2f ap01 = L * gp01, ap23 = L * gp23;     // v_pk_mul
            v2f an01 = L * gn01, an23 = L * gn23;
            v2f ep01, ep23, en01, en23;
            ep01.x = __builtin_amdgcn_exp2f(ap01.x); ep01.y = __builtin_amdgcn_exp2f(ap01.y);
            ep23.x = __builtin_amdgcn_exp2f(ap23.x); ep23.y = __builtin_amdgcn_exp2f(ap23.y);
            en01.x = __builtin_amdgcn_exp2f(an01.x); en01.y = __builtin_amdgcn_exp2f(an01.y);
            en23.x = __builtin_amdgcn_exp2f(an23.x); en23.y = __builtin_amdgcn_exp2f(an23.y);

            v2f u01 = ep01 - en01, u23 = ep23 - en23; // v_pk_add
            accB01 += s * u01;                        // v_pk_fma (s broadcast)
            accB23 += s * u23;
            v2f v01 = wp01 * u01 + wd01 * en01;       // pk_mul + pk_fma
            v2f v23 = wp23 * u23 + wd23 * en23;
            accA01 += s * v01;
            accA23 += s * v23;
        }
    }

    // ---- write A/B partials (coalesced float4) ----
    {
        size_t base = (size_t)bz * (NB * N_OUT) + (b0 + bl) * N_OUT + j0 + tj4 * 4;
        *(float4*)&ws[AOFF + base] = make_float4(accA01.x, accA01.y, accA23.x, accA23.y);
        *(float4*)&ws[BOFF + base] = make_float4(accB01.x, accB01.y, accB23.x, accB23.y);
    }

    // ---- tile weight-max slot (one writer set: by==0) ----
    if (by == 0) {
        __syncthreads();                 // all Lx reads done; safe to alias
        float* qred = &Lx[0][0][0];
        #pragma unroll
        for (int off = 32; off; off >>= 1) m_w = fmaxf(m_w, __shfl_xor(m_w, off));
        if ((tid & 63) == 0) qred[tid >> 6] = m_w;
        __syncthreads();
        if (tid == 0)
            ws[jx * Z + bz] = fmaxf(fmaxf(qred[0], qred[1]), fmaxf(qred[2], qred[3]));
    }
}

__global__ void reduce_combine(const float* __restrict__ ws,
                               const float* __restrict__ bp,
                               const float* __restrict__ bn,
                               const float* __restrict__ npar,
                               float* __restrict__ out) {
    __shared__ float qs[4];
    const int tid = threadIdx.x;

    // q = max(256 tile slots, bias weights) / 9
    float mm = ws[tid];                       // 256 slots over 256 threads
    float2 a2 = ((const float2*)bp)[tid];     // 512 floats over 256 threads
    float2 b2 = ((const float2*)bn)[tid];
    mm = fmaxf(mm, fmaxf(fmaxf(a2.x, a2.y), fmaxf(b2.x, b2.y)));
    #pragma unroll
    for (int off = 32; off; off >>= 1) mm = fmaxf(mm, __shfl_xor(mm, off));
    if ((tid & 63) == 0) qs[tid >> 6] = mm;
    __syncthreads();
    const float q = fmaxf(fmaxf(qs[0], qs[1]), fmaxf(qs[2], qs[3])) * (1.0f / 9.0f);

    const int g = blockIdx.x * 256 + tid;     // float4 index, 0..16383
    const float4* A4 = (const float4*)(ws + AOFF);
    const float4* B4 = (const float4*)(ws + BOFF);
    float ax = 0.f, ay = 0.f, az = 0.f, aw = 0.f;
    float bx = 0.f, byy = 0.f, bz2 = 0.f, bw = 0.f;
    #pragma unroll 8
    for (int z = 0; z < Z; ++z) {
        float4 va = A4[(size_t)z * (NB * N_OUT / 4) + g];
        float4 vb = B4[(size_t)z * (NB * N_OUT / 4) + g];
        ax += va.x; ay += va.y; az += va.z; aw += va.w;
        bx += vb.x; byy += vb.y; bz2 += vb.z; bw += vb.w;
    }
    const int j = (g * 4) & (N_OUT - 1);
    float4 bpv = *(const float4*)&bp[j];
    float4 bnv = *(const float4*)&bn[j];
    const float* nrow = &npar[N_IN * (2 * N_OUT) + 2 * j];
    float4 n0 = *(const float4*)&nrow[0];     // (np0,nn0,np1,nn1)
    float4 n1 = *(const float4*)&nrow[4];     // (np2,nn2,np3,nn3)
    float y0 = 0.5f * (ax + bpv.x * n0.x - bnv.x * n0.y + q * (bx  + n0.x - n0.y));
    float y1 = 0.5f * (ay + bpv.y * n0.z - bnv.y * n0.w + q * (byy + n0.z - n0.w));
    float y2 = 0.5f * (az + bpv.z * n1.x - bnv.z * n1.y + q * (bz2 + n1.x - n1.y));
    float y3 = 0.5f * (aw + bpv.w * n1.z - bnv.w * n1.w + q * (bw  + n1.z - n1.w));
    ((float4*)out)[g] = make_float4(y0, y1, y2, y3);
}

extern "C" void kernel_launch(void* const* d_in, const int* in_sizes, int n_in,
                              void* d_out, int out_size, void* d_ws, size_t ws_size,
                              hipStream_t stream) {
    const float* x    = (const float*)d_in[0];
    const float* wp   = (const float*)d_in[1];
    const float* wn   = (const float*)d_in[2];
    const float* bp   = (const float*)d_in[3];
    const float* bn   = (const float*)d_in[4];
    const float* npar = (const float*)d_in[5];
    float* out = (float*)d_out;
    float* ws  = (float*)d_ws;   // 256 slots + 16 MiB A/B partials

    dim3 grid(N_OUT / JT, NB / BT, Z);   // (8,8,32) = 2048 blocks, 8/CU
    memristor_mainAB<<<grid, 256, 0, stream>>>(x, wp, wn, npar, ws);

    reduce_combine<<<(NB * N_OUT / 4) / 256, 256, 0, stream>>>(ws, bp, bn, npar, out);
}